// Round 8
// baseline (76.203 us; speedup 1.0000x reference)
//
#include <hip/hip_runtime.h>
#include <hip/hip_bf16.h>

#define N_ROWS 32768
#define K_DIM 512
#define OUT_DIM 512
#define N_TYPES 8
#define NB 520              // max 64-row blocks after per-type padding
#define BM 64
#define BN 128
#define BK 64
#define NT (K_DIM / BK)     // 8 K-tiles

typedef __attribute__((ext_vector_type(8))) short bf16x8;
typedef __attribute__((ext_vector_type(4))) float f32x4;

__device__ inline ushort f2bf(float f) {
    __hip_bfloat16 h = __float2bfloat16(f);
    return *reinterpret_cast<ushort*>(&h);
}

__device__ inline void gload_lds16(const void* g, void* l) {
    __builtin_amdgcn_global_load_lds(
        (const __attribute__((address_space(1))) void*)g,
        (__attribute__((address_space(3))) void*)l, 16, 0, 0);
}

// meta layout (ints): [0..7] counts, [8..16] padded bases pbase[0..8]
//                     (pbase[8]=meta[16]=padded total), [20..27] cursors
__global__ void k_init(int* meta) {
    if (threadIdx.x < 32) meta[threadIdx.x] = 0;
}

__global__ void k_hist(const int* __restrict__ x_type, int* meta) {
    __shared__ int cnt[N_TYPES];
    if (threadIdx.x < N_TYPES) cnt[threadIdx.x] = 0;
    __syncthreads();
    int i = blockIdx.x * 256 + threadIdx.x;
    atomicAdd(&cnt[x_type[i]], 1);
    __syncthreads();
    if (threadIdx.x < N_TYPES && cnt[threadIdx.x] > 0)
        atomicAdd(&meta[threadIdx.x], cnt[threadIdx.x]);
}

__global__ void k_scan(int* meta) {
    if (threadIdx.x == 0) {
        int s = 0;
        for (int t = 0; t < N_TYPES; ++t) {
            meta[8 + t]  = s;      // padded base
            meta[20 + t] = s;      // cursor
            s += (meta[t] + 63) & ~63;
        }
        meta[16] = s;              // padded total
    }
}

// per-block LDS hist -> reserve range with 8 global atomics -> scatter
// (row_ids pre-filled with -1; pad slots stay -1)
__global__ void k_fill(const int* __restrict__ x_type, int* meta, int* __restrict__ row_ids) {
    __shared__ int lcnt[N_TYPES];
    __shared__ int lbase[N_TYPES];
    if (threadIdx.x < N_TYPES) lcnt[threadIdx.x] = 0;
    __syncthreads();
    int i = blockIdx.x * 256 + threadIdx.x;
    int t = x_type[i];
    int lpos = atomicAdd(&lcnt[t], 1);
    __syncthreads();
    if (threadIdx.x < N_TYPES)
        lbase[threadIdx.x] = (lcnt[threadIdx.x] > 0)
            ? atomicAdd(&meta[20 + threadIdx.x], lcnt[threadIdx.x]) : 0;
    __syncthreads();
    row_ids[lbase[t] + lpos] = i;
}

// W[t][k][c] fp32 -> Wt[t][c][k] bf16   (64x64 tiles through LDS)
__global__ void k_wt(const float* __restrict__ W, ushort* __restrict__ Wt) {
    __shared__ float tile[64][65];
    int t = blockIdx.x, kb = blockIdx.y, cb = blockIdx.z;
    const float* src = W + (size_t)t * K_DIM * OUT_DIM + (size_t)kb * 64 * OUT_DIM + cb * 64;
    #pragma unroll
    for (int j = 0; j < 16; ++j) {
        int idx = threadIdx.x + j * 256;
        int r = idx >> 6, c = idx & 63;
        tile[r][c] = src[(size_t)r * OUT_DIM + c];
    }
    __syncthreads();
    ushort* dst = Wt + (size_t)t * OUT_DIM * K_DIM + (size_t)(cb * 64) * K_DIM + kb * 64;
    #pragma unroll
    for (int j = 0; j < 16; ++j) {
        int idx = threadIdx.x + j * 256;
        int cc = idx >> 6, kk = idx & 63;
        dst[(size_t)cc * K_DIM + kk] = f2bf(tile[kk][cc]);
    }
}

// 64x128 tiles, 8 waves (wave = 32x32 output), BK=64 DOUBLE-buffered:
// LDS = 2x8KB (A) + 2x16KB (B) = 48KB -> 3 blocks/CU, 24 waves/CU.
// 2-phase: stage t+1 (B gload_lds + A global loads) before compute of t;
// A convert+ds_write after compute (T14); one barrier per K-step.
__global__ __launch_bounds__(512, 4) void k_gemm7(
    const float* __restrict__ x, const ushort* __restrict__ Wt,
    const int* __restrict__ meta, const int* __restrict__ row_ids,
    float* __restrict__ out) {

    __shared__ ushort As[2 * BM * BK];   // 2 x 8 KB,  byte ^= (row&7)<<4
    __shared__ ushort Bs[2 * BN * BK];   // 2 x 16 KB, byte ^= (col&7)<<4
    __shared__ int rids[BM];

    int b = blockIdx.y;
    int r0 = b * BM;
    if (r0 >= meta[16]) return;
    int type = 0;
    #pragma unroll
    for (int t = 0; t < N_TYPES; ++t)
        if (r0 >= meta[8 + t]) type = t;

    int tid = threadIdx.x;
    int wave = tid >> 6, lane = tid & 63;

    if (tid < BM) rids[tid] = row_ids[r0 + tid];
    __syncthreads();

    int c0 = blockIdx.x * BN;
    const ushort* Wtt = Wt + (size_t)type * OUT_DIM * K_DIM + (size_t)c0 * K_DIM;

    // ---- A staging role: thread -> (row, 8-elem slot) ----
    int sa_row  = tid >> 3;
    int sa_slot = tid & 7;
    int sa_rid  = rids[sa_row];
    const float* sa_src = x + (size_t)max(sa_rid, 0) * K_DIM + sa_slot * 8;
    int sa_byte = (sa_row * 128 + sa_slot * 16) ^ ((sa_row & 7) << 4);

    // ---- B staging role: per-lane source swizzle (rule #21: linear dest,
    //      inverse-swz source, swz read) ----
    int sb_colgrp = lane >> 3;                               // 0..7
    int sb_koff   = (((lane & 7) * 16) ^ (sb_colgrp << 4)) >> 1;  // elems

    int wrb = (wave >> 2) * 32;      // wave row base (0/32)
    int wcb = (wave & 3) * 32;       // wave col base (0..96)
    int lrow = lane & 15;
    int lkb16 = (lane >> 4) * 16;    // 16B k-fragment offset

    f32x4 acc[2][2] = {};

#define STAGE_B(buf, kk)                                                        \
    _Pragma("unroll")                                                           \
    for (int j = 0; j < 2; ++j) {                                               \
        int chunk = wave * 2 + j;                                               \
        int col = chunk * 8 + sb_colgrp;                                        \
        gload_lds16(Wtt + (size_t)col * K_DIM + (kk) + sb_koff,                 \
                    (char*)Bs + (buf) * 16384 + chunk * 1024);                  \
    }

#define WRITE_A(buf, v0, v1)                                                    \
    {                                                                           \
        ushort tmp[8] = {0, 0, 0, 0, 0, 0, 0, 0};                               \
        if (sa_rid >= 0) {                                                      \
            tmp[0] = f2bf(v0.x); tmp[1] = f2bf(v0.y);                           \
            tmp[2] = f2bf(v0.z); tmp[3] = f2bf(v0.w);                           \
            tmp[4] = f2bf(v1.x); tmp[5] = f2bf(v1.y);                           \
            tmp[6] = f2bf(v1.z); tmp[7] = f2bf(v1.w);                           \
        }                                                                       \
        *reinterpret_cast<uint4*>((char*)As + (buf) * 8192 + sa_byte) =         \
            *reinterpret_cast<const uint4*>(tmp);                               \
    }

#define COMPUTE(buf)                                                            \
    _Pragma("unroll")                                                           \
    for (int s = 0; s < 2; ++s) {                                               \
        bf16x8 af[2], bfr[2];                                                   \
        _Pragma("unroll")                                                       \
        for (int mi = 0; mi < 2; ++mi) {                                        \
            int row = wrb + mi * 16 + lrow;                                     \
            int byte = (row * 128 + s * 64 + lkb16) ^ ((row & 7) << 4);         \
            af[mi] = *reinterpret_cast<const bf16x8*>(                          \
                (const char*)As + (buf) * 8192 + byte);                         \
        }                                                                       \
        _Pragma("unroll")                                                       \
        for (int ni = 0; ni < 2; ++ni) {                                        \
            int col = wcb + ni * 16 + lrow;                                     \
            int byte = (col * 128 + s * 64 + lkb16) ^ ((col & 7) << 4);         \
            bfr[ni] = *reinterpret_cast<const bf16x8*>(                         \
                (const char*)Bs + (buf) * 16384 + byte);                        \
        }                                                                       \
        _Pragma("unroll")                                                       \
        for (int mi = 0; mi < 2; ++mi)                                          \
            _Pragma("unroll")                                                   \
            for (int ni = 0; ni < 2; ++ni)                                      \
                acc[mi][ni] = __builtin_amdgcn_mfma_f32_16x16x32_bf16(          \
                    af[mi], bfr[ni], acc[mi][ni], 0, 0, 0);                     \
    }

    // ---- prologue: stage tile 0 into buf 0 ----
    STAGE_B(0, 0)
    {
        float4 v0 = {0,0,0,0}, v1 = {0,0,0,0};
        if (sa_rid >= 0) {
            v0 = *reinterpret_cast<const float4*>(sa_src);
            v1 = *reinterpret_cast<const float4*>(sa_src + 4);
        }
        WRITE_A(0, v0, v1)
    }
    __syncthreads();

    // ---- 2-phase main loop: stage t+1 issued before compute of t ----
    #pragma unroll 2
    for (int t = 0; t < NT; ++t) {
        int cur = t & 1;
        float4 v0 = {0,0,0,0}, v1 = {0,0,0,0};
        if (t < NT - 1) {
            STAGE_B(cur ^ 1, (t + 1) * BK)
            if (sa_rid >= 0) {
                v0 = *reinterpret_cast<const float4*>(sa_src + (t + 1) * BK);
                v1 = *reinterpret_cast<const float4*>(sa_src + (t + 1) * BK + 4);
            }
        }
        COMPUTE(cur)
        if (t < NT - 1) {
            WRITE_A(cur ^ 1, v0, v1)
            __syncthreads();   // drains B-stage vmcnt after compute overlap
        }
    }

    // epilogue: D row = (lane>>4)*4 + rr, col = lane&15
    int rgrp = (lane >> 4) * 4;
    #pragma unroll
    for (int mi = 0; mi < 2; ++mi) {
        #pragma unroll
        for (int rr = 0; rr < 4; ++rr) {
            int lr = wrb + mi * 16 + rgrp + rr;
            int gr = rids[lr];
            if (gr >= 0) {
                float* dst = out + (size_t)gr * OUT_DIM + c0 + wcb;
                #pragma unroll
                for (int ni = 0; ni < 2; ++ni)
                    dst[ni * 16 + lrow] = acc[mi][ni][rr];
            }
        }
    }
}

extern "C" void kernel_launch(void* const* d_in, const int* in_sizes, int n_in,
                              void* d_out, int out_size, void* d_ws, size_t ws_size,
                              hipStream_t stream) {
    const float* x      = (const float*)d_in[0];
    const int*   x_type = (const int*)d_in[1];
    const float* W      = (const float*)d_in[2];
    float* out          = (float*)d_out;

    char* ws = (char*)d_ws;
    size_t off_rids = 256;
    size_t off_wt   = off_rids + sizeof(int) * (NB * 64);
    int* meta    = (int*)ws;
    int* row_ids = (int*)(ws + off_rids);
    ushort* Wt   = (ushort*)(ws + off_wt);                  // 4 MB bf16

    k_init<<<1, 64, 0, stream>>>(meta);
    k_hist<<<N_ROWS / 256, 256, 0, stream>>>(x_type, meta);
    k_scan<<<1, 64, 0, stream>>>(meta);
    hipMemsetAsync(row_ids, 0xFF, sizeof(int) * (NB * 64), stream);
    k_fill<<<N_ROWS / 256, 256, 0, stream>>>(x_type, meta, row_ids);

    dim3 wgrid(N_TYPES, K_DIM / 64, OUT_DIM / 64);
    k_wt<<<wgrid, 256, 0, stream>>>(W, Wt);

    // col tiles fastest-varying: x rows of a row-block stay L2-resident
    dim3 ggrid(OUT_DIM / BN, NB);
    k_gemm7<<<ggrid, 512, 0, stream>>>(x, Wt, meta, row_ids, out);
}